// Round 4
// baseline (1147.952 us; speedup 1.0000x reference)
//
#include <hip/hip_runtime.h>
#include <stdint.h>

#define N_NODES 100000
#define N_EDGES 1600000
#define EAD 7
#define H 64
#define LAT 32
#define NG 512
#define NC 6

static_assert(N_NODES % 8 == 0, "node grid divisibility");
static_assert(N_EDGES % 4 == 0, "edge grid divisibility");

// ---------------- Threefry-2x32-20, key = (0, 42)  (jax.random.key(42)) ----
__device__ __forceinline__ void threefry2x32_42(uint32_t& x0, uint32_t& x1) {
    const uint32_t k0 = 0u, k1 = 42u;
    const uint32_t k2 = k0 ^ k1 ^ 0x1BD11BDAu;
    x0 += k0; x1 += k1;
#define TF_ROUND(r) { x0 += x1; x1 = (x1 << (r)) | (x1 >> (32 - (r))); x1 ^= x0; }
    TF_ROUND(13) TF_ROUND(15) TF_ROUND(26) TF_ROUND(6)
    x0 += k1; x1 += k2 + 1u;
    TF_ROUND(17) TF_ROUND(29) TF_ROUND(16) TF_ROUND(24)
    x0 += k2; x1 += k0 + 2u;
    TF_ROUND(13) TF_ROUND(15) TF_ROUND(26) TF_ROUND(6)
    x0 += k0; x1 += k1 + 3u;
    TF_ROUND(17) TF_ROUND(29) TF_ROUND(16) TF_ROUND(24)
    x0 += k1; x1 += k2 + 4u;
    TF_ROUND(13) TF_ROUND(15) TF_ROUND(26) TF_ROUND(6)
    x0 += k2; x1 += k0 + 5u;
#undef TF_ROUND
}

// XLA f32 ErfInv (Giles): matches jax.lax.erf_inv on f32 to ~1 ulp of the poly
__device__ __forceinline__ float erfinv_f32(float x) {
    float w = -log1pf(-x * x);
    float p;
    if (w < 5.0f) {
        w = w - 2.5f;
        p = 2.81022636e-08f;
        p = fmaf(p, w, 3.43273939e-07f);
        p = fmaf(p, w, -3.5233877e-06f);
        p = fmaf(p, w, -4.39150654e-06f);
        p = fmaf(p, w, 0.00021858087f);
        p = fmaf(p, w, -0.00125372503f);
        p = fmaf(p, w, -0.00417768164f);
        p = fmaf(p, w, 0.246640727f);
        p = fmaf(p, w, 1.50140941f);
    } else {
        w = sqrtf(w) - 3.0f;
        p = -0.000200214257f;
        p = fmaf(p, w, 0.000100950558f);
        p = fmaf(p, w, 0.00134934322f);
        p = fmaf(p, w, -0.00367342844f);
        p = fmaf(p, w, 0.00573950773f);
        p = fmaf(p, w, -0.0076224613f);
        p = fmaf(p, w, 0.00943887047f);
        p = fmaf(p, w, 1.00167406f);
        p = fmaf(p, w, 2.83297682f);
    }
    return p * x;
}

// ---------------- conv1: scalar edge messages --------------------------------
__global__ void conv1_edge(const float* __restrict__ x, const int* __restrict__ src,
                           const int* __restrict__ dst, const float* __restrict__ ea,
                           const float* __restrict__ We1, const float* __restrict__ be1,
                           float* __restrict__ agg1) {
    int e = blockIdx.x * blockDim.x + threadIdx.x;
    if (e >= N_EDGES) return;
    float proj = be1[0];
#pragma unroll
    for (int k = 0; k < EAD; k++) proj = fmaf(ea[e * EAD + k], We1[k], proj);
    float m = x[src[e]] + proj;
    m = m > 0.0f ? m : 0.0f;
    atomicAdd(&agg1[dst[e]], m);
}

// ---------------- conv1: per-node MLP 1 -> 64 -> 64, outer relu -------------
__global__ void conv1_node(const float* __restrict__ x, const float* __restrict__ agg1,
                           const float* __restrict__ W11, const float* __restrict__ b11,
                           const float* __restrict__ W12, const float* __restrict__ b12,
                           const float* __restrict__ eps1, float* __restrict__ hout) {
    __shared__ float sW12[H * H];
    __shared__ float st[4][H];
    int tid = threadIdx.x;
    for (int i = tid; i < H * H; i += 256) sW12[i] = W12[i];
    int sub = tid >> 6, lane = tid & 63;
    int n = blockIdx.x * 4 + sub;
    float h1 = fmaf(eps1[0], x[n], x[n]) + agg1[n];   // (1+eps)*x + agg
    float t = fmaf(h1, W11[lane], b11[lane]);
    st[sub][lane] = t > 0.0f ? t : 0.0f;
    __syncthreads();
    float acc = b12[lane];
#pragma unroll
    for (int j = 0; j < H; j++) acc = fmaf(st[sub][j], sW12[j * H + lane], acc);
    hout[(size_t)n * H + lane] = acc > 0.0f ? acc : 0.0f;  // outer relu
}

// ---------------- conv2: 64-wide edge messages + atomic scatter -------------
__global__ void conv2_edge(const float* __restrict__ h, const int* __restrict__ src,
                           const int* __restrict__ dst, const float* __restrict__ ea,
                           const float* __restrict__ We2, const float* __restrict__ be2,
                           float* __restrict__ agg2) {
    int lane = threadIdx.x & 63;
    int e = (blockIdx.x * blockDim.x + threadIdx.x) >> 6;
    if (e >= N_EDGES) return;
    int s = src[e], d = dst[e];
    float proj = be2[lane];
#pragma unroll
    for (int k = 0; k < EAD; k++) proj = fmaf(ea[e * EAD + k], We2[k * H + lane], proj);
    float m = h[(size_t)s * H + lane] + proj;
    m = m > 0.0f ? m : 0.0f;
    atomicAdd(&agg2[(size_t)d * H + lane], m);
}

// ---------------- conv2: per-node MLP 64 -> 64 -> 64, outer relu ------------
// hout may alias agg2 (each thread reads its element before writing it)
__global__ void conv2_node(const float* __restrict__ hin, const float* __restrict__ agg2,
                           const float* __restrict__ W21, const float* __restrict__ b21,
                           const float* __restrict__ W22, const float* __restrict__ b22,
                           const float* __restrict__ eps2, float* __restrict__ hout) {
    __shared__ float sW21[H * H], sW22[H * H];
    __shared__ float sh2[4][H], st[4][H];
    int tid = threadIdx.x;
    for (int i = tid; i < H * H; i += 256) { sW21[i] = W21[i]; sW22[i] = W22[i]; }
    int sub = tid >> 6, lane = tid & 63;
    int n = blockIdx.x * 4 + sub;
    float e = eps2[0];
    float hv = hin[(size_t)n * H + lane];
    sh2[sub][lane] = fmaf(e, hv, hv) + agg2[(size_t)n * H + lane];
    __syncthreads();
    float acc = b21[lane];
#pragma unroll
    for (int j = 0; j < H; j++) acc = fmaf(sh2[sub][j], sW21[j * H + lane], acc);
    st[sub][lane] = acc > 0.0f ? acc : 0.0f;
    __syncthreads();
    acc = b22[lane];
#pragma unroll
    for (int j = 0; j < H; j++) acc = fmaf(st[sub][j], sW22[j * H + lane], acc);
    hout[(size_t)n * H + lane] = acc > 0.0f ? acc : 0.0f;  // outer relu
}

// ---------------- heads: mu/logvar GEMVs + JAX-exact noise + z + pool -------
__global__ void heads_k(const float* __restrict__ h, const int* __restrict__ batch,
                        const float* __restrict__ Wmu, const float* __restrict__ bmu,
                        const float* __restrict__ Wlv, const float* __restrict__ blv,
                        float* __restrict__ z_out, float* __restrict__ mu_out,
                        float* __restrict__ lv_out,
                        float* __restrict__ zsum, float* __restrict__ cnt) {
    __shared__ float sWmu[H * LAT], sWlv[H * LAT];
    __shared__ float sh[8][H];
    int tid = threadIdx.x;
    for (int i = tid; i < H * LAT; i += 256) { sWmu[i] = Wmu[i]; sWlv[i] = Wlv[i]; }
    for (int i = tid; i < 8 * H; i += 256)
        sh[i >> 6][i & 63] = h[(size_t)blockIdx.x * 8 * H + i];
    __syncthreads();
    int sub = tid >> 5, lane = tid & 31;
    int n = blockIdx.x * 8 + sub;
    float mu = bmu[lane], lv = blv[lane];
#pragma unroll
    for (int j = 0; j < H; j++) {
        float hv = sh[sub][j];
        mu = fmaf(hv, sWmu[j * LAT + lane], mu);
        lv = fmaf(hv, sWlv[j * LAT + lane], lv);
    }
    // JAX noise, partitionable threefry (default since jax 0.4.30):
    //   counts1, counts2 = iota_2x32_shape(shape)          -> (0, j) here
    //   bits1, bits2 = threefry2x32(key, counts1, counts2)
    //   bit_width==32: return bits1 ^ bits2                -> XOR-FOLD of both words
    uint32_t j = (uint32_t)(n * LAT + lane);
    uint32_t x0 = 0u, x1 = j;          // (counts_hi, counts_lo)
    threefry2x32_42(x0, x1);
    uint32_t bits = x0 ^ x1;           // xor-fold 64 output bits -> 32
    float f = __uint_as_float((bits >> 9) | 0x3F800000u) - 1.0f;   // [0,1)
    const float lo = -0.99999994f;                                  // nextafter(-1,0)
    float u = fmaxf(lo, fmaf(f, 2.0f, lo));                         // f*2 exact -> fma == mul+add
    float noise = 1.41421356237309515f * erfinv_f32(u);
    float zv = fmaf(noise, expf(0.5f * lv), mu);

    size_t o = (size_t)n * LAT + lane;
    z_out[o] = zv; mu_out[o] = mu; lv_out[o] = lv;

    int g = batch[n];
    atomicAdd(&zsum[g * LAT + lane], zv);
    if (lane == 0) atomicAdd(&cnt[g], 1.0f);
}

// ---------------- graph logits ---------------------------------------------
__global__ void logits_k(const float* __restrict__ zsum, const float* __restrict__ cnt,
                         const float* __restrict__ Wc, const float* __restrict__ bc,
                         float* __restrict__ out) {
    int g = blockIdx.x * blockDim.x + threadIdx.x;
    if (g >= NG) return;
    float inv = 1.0f / fmaxf(cnt[g], 1.0f);
    float emb[LAT];
#pragma unroll
    for (int l = 0; l < LAT; l++) emb[l] = zsum[g * LAT + l] * inv;
#pragma unroll
    for (int c = 0; c < NC; c++) {
        float acc = bc[c];
#pragma unroll
        for (int l = 0; l < LAT; l++) acc = fmaf(emb[l], Wc[l * NC + c], acc);
        out[g * NC + c] = acc;
    }
}

extern "C" void kernel_launch(void* const* d_in, const int* in_sizes, int n_in,
                              void* d_out, int out_size, void* d_ws, size_t ws_size,
                              hipStream_t stream) {
    const float* x     = (const float*)d_in[0];
    const int*   ei    = (const int*)d_in[1];
    const float* ea    = (const float*)d_in[2];
    const int*   batch = (const int*)d_in[3];
    const float* We1   = (const float*)d_in[4];
    const float* be1   = (const float*)d_in[5];
    const float* W11   = (const float*)d_in[6];
    const float* b11   = (const float*)d_in[7];
    const float* W12   = (const float*)d_in[8];
    const float* b12   = (const float*)d_in[9];
    const float* eps1  = (const float*)d_in[10];
    const float* We2   = (const float*)d_in[11];
    const float* be2   = (const float*)d_in[12];
    const float* W21   = (const float*)d_in[13];
    const float* b21   = (const float*)d_in[14];
    const float* W22   = (const float*)d_in[15];
    const float* b22   = (const float*)d_in[16];
    const float* eps2  = (const float*)d_in[17];
    const float* Wmu   = (const float*)d_in[18];
    const float* bmu   = (const float*)d_in[19];
    const float* Wlv   = (const float*)d_in[20];
    const float* blv   = (const float*)d_in[21];
    const float* Wc    = (const float*)d_in[22];
    const float* bc    = (const float*)d_in[23];

    // workspace layout: [agg1 N][agg2 N*H][zsum G*L][cnt G] <- zeroed; [hA N*H]
    // hB aliases agg2 (conv2_node reads each element before overwriting it).
    float* agg1 = (float*)d_ws;
    float* agg2 = agg1 + N_NODES;
    float* zsum = agg2 + (size_t)N_NODES * H;
    float* cnt  = zsum + NG * LAT;
    float* hA   = cnt + NG;
    float* hB   = agg2;  // alias

    size_t zero_bytes = ((size_t)N_NODES + (size_t)N_NODES * H + NG * LAT + NG) * sizeof(float);
    hipMemsetAsync(d_ws, 0, zero_bytes, stream);

    const int* src = ei;
    const int* dst = ei + N_EDGES;

    float* z_out     = (float*)d_out;
    float* mu_out    = z_out + (size_t)N_NODES * LAT;
    float* lv_out    = mu_out + (size_t)N_NODES * LAT;
    float* logit_out = lv_out + (size_t)N_NODES * LAT;

    conv1_edge<<<(N_EDGES + 255) / 256, 256, 0, stream>>>(x, src, dst, ea, We1, be1, agg1);
    conv1_node<<<N_NODES / 4, 256, 0, stream>>>(x, agg1, W11, b11, W12, b12, eps1, hA);
    conv2_edge<<<N_EDGES / 4, 256, 0, stream>>>(hA, src, dst, ea, We2, be2, agg2);
    conv2_node<<<N_NODES / 4, 256, 0, stream>>>(hA, agg2, W21, b21, W22, b22, eps2, hB);
    heads_k<<<N_NODES / 8, 256, 0, stream>>>(hB, batch, Wmu, bmu, Wlv, blv,
                                             z_out, mu_out, lv_out, zsum, cnt);
    logits_k<<<(NG + 63) / 64, 64, 0, stream>>>(zsum, cnt, Wc, bc, logit_out);
}

// Round 5
// 1037.200 us; speedup vs baseline: 1.1068x; 1.1068x over previous
//
#include <hip/hip_runtime.h>
#include <stdint.h>

#define N_NODES 100000
#define N_EDGES 1600000
#define EAD 7
#define H 64
#define LAT 32
#define NG 512
#define NC 6

static_assert(N_NODES % 8 == 0, "node grid divisibility");
static_assert(N_EDGES % 4 == 0, "edge grid divisibility");

// ---------------- Threefry-2x32-20, key = (0, 42)  (jax.random.key(42)) ----
__device__ __forceinline__ void threefry2x32_42(uint32_t& x0, uint32_t& x1) {
    const uint32_t k0 = 0u, k1 = 42u;
    const uint32_t k2 = k0 ^ k1 ^ 0x1BD11BDAu;
    x0 += k0; x1 += k1;
#define TF_ROUND(r) { x0 += x1; x1 = (x1 << (r)) | (x1 >> (32 - (r))); x1 ^= x0; }
    TF_ROUND(13) TF_ROUND(15) TF_ROUND(26) TF_ROUND(6)
    x0 += k1; x1 += k2 + 1u;
    TF_ROUND(17) TF_ROUND(29) TF_ROUND(16) TF_ROUND(24)
    x0 += k2; x1 += k0 + 2u;
    TF_ROUND(13) TF_ROUND(15) TF_ROUND(26) TF_ROUND(6)
    x0 += k0; x1 += k1 + 3u;
    TF_ROUND(17) TF_ROUND(29) TF_ROUND(16) TF_ROUND(24)
    x0 += k1; x1 += k2 + 4u;
    TF_ROUND(13) TF_ROUND(15) TF_ROUND(26) TF_ROUND(6)
    x0 += k2; x1 += k0 + 5u;
#undef TF_ROUND
}

// XLA f32 ErfInv (Giles): matches jax.lax.erf_inv on f32 to ~1 ulp of the poly
__device__ __forceinline__ float erfinv_f32(float x) {
    float w = -log1pf(-x * x);
    float p;
    if (w < 5.0f) {
        w = w - 2.5f;
        p = 2.81022636e-08f;
        p = fmaf(p, w, 3.43273939e-07f);
        p = fmaf(p, w, -3.5233877e-06f);
        p = fmaf(p, w, -4.39150654e-06f);
        p = fmaf(p, w, 0.00021858087f);
        p = fmaf(p, w, -0.00125372503f);
        p = fmaf(p, w, -0.00417768164f);
        p = fmaf(p, w, 0.246640727f);
        p = fmaf(p, w, 1.50140941f);
    } else {
        w = sqrtf(w) - 3.0f;
        p = -0.000200214257f;
        p = fmaf(p, w, 0.000100950558f);
        p = fmaf(p, w, 0.00134934322f);
        p = fmaf(p, w, -0.00367342844f);
        p = fmaf(p, w, 0.00573950773f);
        p = fmaf(p, w, -0.0076224613f);
        p = fmaf(p, w, 0.00943887047f);
        p = fmaf(p, w, 1.00167406f);
        p = fmaf(p, w, 2.83297682f);
    }
    return p * x;
}

// ---------------- conv1: scalar edge messages --------------------------------
__global__ void conv1_edge(const float* __restrict__ x, const int* __restrict__ src,
                           const int* __restrict__ dst, const float* __restrict__ ea,
                           const float* __restrict__ We1, const float* __restrict__ be1,
                           float* __restrict__ agg1) {
    int e = blockIdx.x * blockDim.x + threadIdx.x;
    if (e >= N_EDGES) return;
    float proj = be1[0];
#pragma unroll
    for (int k = 0; k < EAD; k++) proj = fmaf(ea[e * EAD + k], We1[k], proj);
    float m = x[src[e]] + proj;
    m = m > 0.0f ? m : 0.0f;
    atomicAdd(&agg1[dst[e]], m);
}

// ---------------- conv1: per-node MLP 1 -> 64 -> 64, outer relu -------------
__global__ void conv1_node(const float* __restrict__ x, const float* __restrict__ agg1,
                           const float* __restrict__ W11, const float* __restrict__ b11,
                           const float* __restrict__ W12, const float* __restrict__ b12,
                           const float* __restrict__ eps1, float* __restrict__ hout) {
    __shared__ float sW12[H * H];
    __shared__ float st[4][H];
    int tid = threadIdx.x;
    for (int i = tid; i < H * H; i += 256) sW12[i] = W12[i];
    int sub = tid >> 6, lane = tid & 63;
    int n = blockIdx.x * 4 + sub;
    float h1 = fmaf(eps1[0], x[n], x[n]) + agg1[n];   // (1+eps)*x + agg
    float t = fmaf(h1, W11[lane], b11[lane]);
    st[sub][lane] = t > 0.0f ? t : 0.0f;
    __syncthreads();
    float acc = b12[lane];
#pragma unroll
    for (int j = 0; j < H; j++) acc = fmaf(st[sub][j], sW12[j * H + lane], acc);
    hout[(size_t)n * H + lane] = acc > 0.0f ? acc : 0.0f;  // outer relu
}

// ---------------- conv2: 64-wide edge messages + atomic scatter -------------
__global__ void conv2_edge(const float* __restrict__ h, const int* __restrict__ src,
                           const int* __restrict__ dst, const float* __restrict__ ea,
                           const float* __restrict__ We2, const float* __restrict__ be2,
                           float* __restrict__ agg2) {
    int lane = threadIdx.x & 63;
    int e = (blockIdx.x * blockDim.x + threadIdx.x) >> 6;
    if (e >= N_EDGES) return;
    int s = src[e], d = dst[e];
    float proj = be2[lane];
#pragma unroll
    for (int k = 0; k < EAD; k++) proj = fmaf(ea[e * EAD + k], We2[k * H + lane], proj);
    float m = h[(size_t)s * H + lane] + proj;
    m = m > 0.0f ? m : 0.0f;
    atomicAdd(&agg2[(size_t)d * H + lane], m);
}

// ---------------- conv2: per-node MLP 64 -> 64 -> 64, outer relu ------------
// hout may alias agg2 (each thread reads its element before writing it)
__global__ void conv2_node(const float* __restrict__ hin, const float* __restrict__ agg2,
                           const float* __restrict__ W21, const float* __restrict__ b21,
                           const float* __restrict__ W22, const float* __restrict__ b22,
                           const float* __restrict__ eps2, float* __restrict__ hout) {
    __shared__ float sW21[H * H], sW22[H * H];
    __shared__ float sh2[4][H], st[4][H];
    int tid = threadIdx.x;
    for (int i = tid; i < H * H; i += 256) { sW21[i] = W21[i]; sW22[i] = W22[i]; }
    int sub = tid >> 6, lane = tid & 63;
    int n = blockIdx.x * 4 + sub;
    float e = eps2[0];
    float hv = hin[(size_t)n * H + lane];
    sh2[sub][lane] = fmaf(e, hv, hv) + agg2[(size_t)n * H + lane];
    __syncthreads();
    float acc = b21[lane];
#pragma unroll
    for (int j = 0; j < H; j++) acc = fmaf(sh2[sub][j], sW21[j * H + lane], acc);
    st[sub][lane] = acc > 0.0f ? acc : 0.0f;
    __syncthreads();
    acc = b22[lane];
#pragma unroll
    for (int j = 0; j < H; j++) acc = fmaf(st[sub][j], sW22[j * H + lane], acc);
    hout[(size_t)n * H + lane] = acc > 0.0f ? acc : 0.0f;  // outer relu
}

// ---------------- heads: mu/logvar GEMVs + JAX-exact noise + z (no atomics) -
__global__ void heads_k(const float* __restrict__ h,
                        const float* __restrict__ Wmu, const float* __restrict__ bmu,
                        const float* __restrict__ Wlv, const float* __restrict__ blv,
                        float* __restrict__ z_out, float* __restrict__ mu_out,
                        float* __restrict__ lv_out) {
    __shared__ float sWmu[H * LAT], sWlv[H * LAT];
    __shared__ float sh[8][H];
    int tid = threadIdx.x;
    for (int i = tid; i < H * LAT; i += 256) { sWmu[i] = Wmu[i]; sWlv[i] = Wlv[i]; }
    for (int i = tid; i < 8 * H; i += 256)
        sh[i >> 6][i & 63] = h[(size_t)blockIdx.x * 8 * H + i];
    __syncthreads();
    int sub = tid >> 5, lane = tid & 31;
    int n = blockIdx.x * 8 + sub;
    float mu = bmu[lane], lv = blv[lane];
#pragma unroll
    for (int j = 0; j < H; j++) {
        float hv = sh[sub][j];
        mu = fmaf(hv, sWmu[j * LAT + lane], mu);
        lv = fmaf(hv, sWlv[j * LAT + lane], lv);
    }
    // JAX partitionable threefry: counter (hi,lo)=(0,j); 32-bit draws XOR-FOLD
    // the two output words (bits1 ^ bits2).  [verified R4: absmax 0.0156]
    uint32_t j = (uint32_t)(n * LAT + lane);
    uint32_t x0 = 0u, x1 = j;
    threefry2x32_42(x0, x1);
    uint32_t bits = x0 ^ x1;
    float f = __uint_as_float((bits >> 9) | 0x3F800000u) - 1.0f;   // [0,1)
    const float lo = -0.99999994f;                                  // nextafter(-1,0)
    float u = fmaxf(lo, fmaf(f, 2.0f, lo));
    float noise = 1.41421356237309515f * erfinv_f32(u);
    float zv = fmaf(noise, expf(0.5f * lv), mu);

    size_t o = (size_t)n * LAT + lane;
    z_out[o] = zv; mu_out[o] = mu; lv_out[o] = lv;
}

// ---------------- pool + logits: one block per graph, batch is SORTED -------
__global__ void pool_logits_k(const float* __restrict__ z, const int* __restrict__ batch,
                              const float* __restrict__ Wc, const float* __restrict__ bc,
                              float* __restrict__ out) {
    int g = blockIdx.x;
    int tid = threadIdx.x, sub = tid >> 5, lane = tid & 31;
    __shared__ float acc[8][LAT];
    __shared__ float emb[LAT];
    // lower_bound(batch, g) and lower_bound(batch, g+1) — batch sorted asc
    int lo = 0, hi = N_NODES;
    while (lo < hi) { int mid = (lo + hi) >> 1; if (batch[mid] < g) lo = mid + 1; else hi = mid; }
    int start = lo;
    hi = N_NODES;
    while (lo < hi) { int mid = (lo + hi) >> 1; if (batch[mid] < g + 1) lo = mid + 1; else hi = mid; }
    int end = lo;
    float a = 0.0f;
    for (int n = start + sub; n < end; n += 8)
        a += z[(size_t)n * LAT + lane];
    acc[sub][lane] = a;
    __syncthreads();
    if (sub == 0) {
        float s = acc[0][lane] + acc[1][lane] + acc[2][lane] + acc[3][lane]
                + acc[4][lane] + acc[5][lane] + acc[6][lane] + acc[7][lane];
        emb[lane] = s / fmaxf((float)(end - start), 1.0f);
    }
    __syncthreads();
    if (tid < NC) {
        float r = bc[tid];
#pragma unroll
        for (int l = 0; l < LAT; l++) r = fmaf(emb[l], Wc[l * NC + tid], r);
        out[g * NC + tid] = r;
    }
}

extern "C" void kernel_launch(void* const* d_in, const int* in_sizes, int n_in,
                              void* d_out, int out_size, void* d_ws, size_t ws_size,
                              hipStream_t stream) {
    const float* x     = (const float*)d_in[0];
    const int*   ei    = (const int*)d_in[1];
    const float* ea    = (const float*)d_in[2];
    const int*   batch = (const int*)d_in[3];
    const float* We1   = (const float*)d_in[4];
    const float* be1   = (const float*)d_in[5];
    const float* W11   = (const float*)d_in[6];
    const float* b11   = (const float*)d_in[7];
    const float* W12   = (const float*)d_in[8];
    const float* b12   = (const float*)d_in[9];
    const float* eps1  = (const float*)d_in[10];
    const float* We2   = (const float*)d_in[11];
    const float* be2   = (const float*)d_in[12];
    const float* W21   = (const float*)d_in[13];
    const float* b21   = (const float*)d_in[14];
    const float* W22   = (const float*)d_in[15];
    const float* b22   = (const float*)d_in[16];
    const float* eps2  = (const float*)d_in[17];
    const float* Wmu   = (const float*)d_in[18];
    const float* bmu   = (const float*)d_in[19];
    const float* Wlv   = (const float*)d_in[20];
    const float* blv   = (const float*)d_in[21];
    const float* Wc    = (const float*)d_in[22];
    const float* bc    = (const float*)d_in[23];

    // workspace layout: [agg1 N][agg2 N*H] <- zeroed; [hA N*H]
    // hB aliases agg2 (conv2_node reads each element before overwriting it).
    float* agg1 = (float*)d_ws;
    float* agg2 = agg1 + N_NODES;
    float* hA   = agg2 + (size_t)N_NODES * H;
    float* hB   = agg2;  // alias

    size_t zero_bytes = ((size_t)N_NODES + (size_t)N_NODES * H) * sizeof(float);
    hipMemsetAsync(d_ws, 0, zero_bytes, stream);

    const int* src = ei;
    const int* dst = ei + N_EDGES;

    float* z_out     = (float*)d_out;
    float* mu_out    = z_out + (size_t)N_NODES * LAT;
    float* lv_out    = mu_out + (size_t)N_NODES * LAT;
    float* logit_out = lv_out + (size_t)N_NODES * LAT;

    conv1_edge<<<(N_EDGES + 255) / 256, 256, 0, stream>>>(x, src, dst, ea, We1, be1, agg1);
    conv1_node<<<N_NODES / 4, 256, 0, stream>>>(x, agg1, W11, b11, W12, b12, eps1, hA);
    conv2_edge<<<N_EDGES / 4, 256, 0, stream>>>(hA, src, dst, ea, We2, be2, agg2);
    conv2_node<<<N_NODES / 4, 256, 0, stream>>>(hA, agg2, W21, b21, W22, b22, eps2, hB);
    heads_k<<<N_NODES / 8, 256, 0, stream>>>(hB, Wmu, bmu, Wlv, blv, z_out, mu_out, lv_out);
    pool_logits_k<<<NG, 256, 0, stream>>>(z_out, batch, Wc, bc, logit_out);
}